// Round 1
// baseline (249.112 us; speedup 1.0000x reference)
//
#include <hip/hip_runtime.h>
#include <cstdint>
#include <cstddef>

// Problem geometry (fixed by the reference setup_inputs()):
//   predictions: (16, 3, 160, 160, 9) fp32  -> per image N=76800 anchors x D=9
//   targets:     (16, 32, 5) fp32  [cls, x, y, w, h]
//   output: 4 fp32 scalars: total, box_loss, cls_loss, obj_loss
constexpr int kB    = 16;
constexpr int kN    = 76800;       // 3*160*160
constexpr int kD    = 9;
constexpr int kT    = 32;
constexpr int kBlk  = 256;
constexpr int kNB   = kN / kBlk;   // 300 blocks per image (exact)
constexpr int kWords = kN / 64;    // 1200 ballot words per image

struct Accum {
  int   npos[kB];
  int   nneg[kB];
  float objPos[kB];
  float objNeg[kB];
  float sqSum[kB];
  float ceSum[kB];
};

// jax.nn.softplus(x) == logaddexp(x,0) == max(x,0) + log1p(exp(-|x|))
__device__ __forceinline__ float softplusf(float x) {
  return fmaxf(x, 0.f) + log1pf(expf(-fabsf(x)));
}

// ---------------------------------------------------------------------------
// Pass 1: per anchor, IoU-max over 32 targets -> pos/neg flags (bit-packed),
// per-block pos counts, per-image npos/nneg/objPos/objNeg partial sums.
// ---------------------------------------------------------------------------
__global__ __launch_bounds__(kBlk) void pass1_kernel(
    const float* __restrict__ pred, const float* __restrict__ tgt,
    Accum* __restrict__ acc, int* __restrict__ blockCounts,
    unsigned long long* __restrict__ posBits)
{
  __shared__ float s_t1x[kT], s_t1y[kT], s_t2x[kT], s_t2y[kT], s_ta[kT];
  __shared__ float s_red[4][2];
  __shared__ int   s_cnt[4][2];

  const int b   = blockIdx.y;
  const int blk = blockIdx.x;
  const int tid = threadIdx.x;

  if (tid < kT) {
    const float* tp = tgt + ((size_t)b * kT + tid) * 5;
    const float tx = tp[1], ty = tp[2], tw = tp[3], th = tp[4];
    const float t1x = tx - tw * 0.5f, t1y = ty - th * 0.5f;
    const float t2x = tx + tw * 0.5f, t2y = ty + th * 0.5f;
    s_t1x[tid] = t1x; s_t1y[tid] = t1y;
    s_t2x[tid] = t2x; s_t2y[tid] = t2y;
    // replicate reference: ta = prod(t2 - t1), not w*h
    s_ta[tid]  = (t2x - t1x) * (t2y - t1y);
  }
  __syncthreads();

  const int i = blk * kBlk + tid;               // always < kN (exact tiling)
  const float* p = pred + ((size_t)b * kN + i) * kD;
  const float px = p[0], py = p[1], pw = p[2], ph = p[3], pobj = p[4];
  const float p1x = px - pw * 0.5f, p1y = py - ph * 0.5f;
  const float p2x = px + pw * 0.5f, p2y = py + ph * 0.5f;
  const float pa  = (p2x - p1x) * (p2y - p1y);  // prod(p2-p1), may be negative

  float best = -INFINITY;
  #pragma unroll
  for (int j = 0; j < kT; ++j) {
    const float lox = fmaxf(p1x, s_t1x[j]);
    const float loy = fmaxf(p1y, s_t1y[j]);
    const float hix = fminf(p2x, s_t2x[j]);
    const float hiy = fminf(p2y, s_t2y[j]);
    const float inter = fmaxf(hix - lox, 0.f) * fmaxf(hiy - loy, 0.f);
    const float iou = inter / (pa + s_ta[j] - inter + 1e-6f);  // exact IEEE div
    best = fmaxf(best, iou);
  }
  const bool pos = best > 0.5f;
  const bool neg = best < 0.3f;

  float op = pos ? softplusf(-pobj) : 0.f;
  float on = neg ? softplusf( pobj) : 0.f;

  const int lane = tid & 63;
  const int wv   = tid >> 6;
  const unsigned long long pmask = __ballot(pos);
  const unsigned long long nmask = __ballot(neg);
  if (lane == 0)
    posBits[(size_t)b * kWords + blk * 4 + wv] = pmask;

  #pragma unroll
  for (int off = 32; off > 0; off >>= 1) {
    op += __shfl_down(op, off, 64);
    on += __shfl_down(on, off, 64);
  }
  if (lane == 0) {
    s_red[wv][0] = op;             s_red[wv][1] = on;
    s_cnt[wv][0] = __popcll(pmask); s_cnt[wv][1] = __popcll(nmask);
  }
  __syncthreads();
  if (tid == 0) {
    float sop = 0.f, son = 0.f; int pc = 0, nc = 0;
    #pragma unroll
    for (int w = 0; w < 4; ++w) {
      sop += s_red[w][0]; son += s_red[w][1];
      pc  += s_cnt[w][0]; nc  += s_cnt[w][1];
    }
    blockCounts[b * kNB + blk] = pc;
    atomicAdd(&acc->npos[b], pc);
    atomicAdd(&acc->nneg[b], nc);
    atomicAdd(&acc->objPos[b], sop);
    atomicAdd(&acc->objNeg[b], son);
  }
}

// ---------------------------------------------------------------------------
// Pass 2: per image, exclusive scan of the 300 per-block pos counts.
// One block per image, 512 threads, Hillis-Steele in LDS.
// ---------------------------------------------------------------------------
__global__ __launch_bounds__(512) void pass2_kernel(
    const int* __restrict__ blockCounts, int* __restrict__ blockOffsets)
{
  __shared__ int s[512];
  const int b = blockIdx.x, t = threadIdx.x;
  const int v = (t < kNB) ? blockCounts[b * kNB + t] : 0;
  s[t] = v;
  __syncthreads();
  for (int off = 1; off < 512; off <<= 1) {
    const int add = (t >= off) ? s[t - off] : 0;
    __syncthreads();
    s[t] += add;
    __syncthreads();
  }
  if (t < kNB) blockOffsets[b * kNB + t] = s[t] - v;  // exclusive
}

// ---------------------------------------------------------------------------
// Pass 3: positives only — ordinal via ballot prefix + block offset,
// tidx = ordinal % 32, accumulate box SSE and class CE.
// ---------------------------------------------------------------------------
__global__ __launch_bounds__(kBlk) void pass3_kernel(
    const float* __restrict__ pred, const float* __restrict__ tgt,
    Accum* __restrict__ acc, const int* __restrict__ blockOffsets,
    const unsigned long long* __restrict__ posBits)
{
  __shared__ float s_tx[kT], s_ty[kT];
  __shared__ int   s_tc[kT];
  __shared__ int   s_wtot[4];
  __shared__ float s_red[4][2];

  const int b = blockIdx.y, blk = blockIdx.x, tid = threadIdx.x;
  if (tid < kT) {
    const float* tp = tgt + ((size_t)b * kT + tid) * 5;
    s_tx[tid] = tp[1]; s_ty[tid] = tp[2];
    s_tc[tid] = (int)tp[0];   // float {0..3} -> int, exact
  }
  const int lane = tid & 63, wv = tid >> 6;
  const unsigned long long mask = posBits[(size_t)b * kWords + blk * 4 + wv];
  if (lane == 0) s_wtot[wv] = __popcll(mask);
  __syncthreads();

  int base = blockOffsets[b * kNB + blk];
  for (int w = 0; w < wv; ++w) base += s_wtot[w];

  const bool pos = (mask >> lane) & 1ull;
  float sqc = 0.f, cec = 0.f;
  if (pos) {
    const int ord = base + __popcll(mask & ((1ull << lane) - 1ull));
    const int tix = ord & (kT - 1);  // % 32, ord >= 0
    const int i = blk * kBlk + tid;
    const float* p = pred + ((size_t)b * kN + i) * kD;
    const float dx = p[0] - s_tx[tix];
    const float dy = p[1] - s_ty[tix];
    sqc = dx * dx + dy * dy;
    const float c0 = p[5], c1 = p[6], c2 = p[7], c3 = p[8];
    const float m = fmaxf(fmaxf(c0, c1), fmaxf(c2, c3));
    const float lse = m + logf(expf(c0 - m) + expf(c1 - m) + expf(c2 - m) + expf(c3 - m));
    const int tc = s_tc[tix];
    const float cv = (tc == 0) ? c0 : (tc == 1) ? c1 : (tc == 2) ? c2 : c3;
    cec = lse - cv;
  }
  #pragma unroll
  for (int off = 32; off > 0; off >>= 1) {
    sqc += __shfl_down(sqc, off, 64);
    cec += __shfl_down(cec, off, 64);
  }
  if (lane == 0) { s_red[wv][0] = sqc; s_red[wv][1] = cec; }
  __syncthreads();
  if (tid == 0) {
    float ss = 0.f, cs = 0.f;
    #pragma unroll
    for (int w = 0; w < 4; ++w) { ss += s_red[w][0]; cs += s_red[w][1]; }
    atomicAdd(&acc->sqSum[b], ss);
    atomicAdd(&acc->ceSum[b], cs);
  }
}

// ---------------------------------------------------------------------------
// Pass 4: finalize 4 scalars.
// ---------------------------------------------------------------------------
__global__ __launch_bounds__(64) void pass4_kernel(
    const Accum* __restrict__ acc, float* __restrict__ out)
{
  const int tid = threadIdx.x;
  float box = 0.f, cls = 0.f, obj = 0.f;
  if (tid < kB) {
    const float np_ = (float)acc->npos[tid];
    const float nn  = (float)acc->nneg[tid];
    if (np_ > 0.f) {
      box = acc->sqSum[tid] / (2.0f * np_);
      cls = acc->ceSum[tid] / np_;
      obj = acc->objPos[tid] / np_;
    }
    if (nn > 0.f) obj += acc->objNeg[tid] / nn;
  }
  #pragma unroll
  for (int off = 32; off > 0; off >>= 1) {
    box += __shfl_down(box, off, 64);
    cls += __shfl_down(cls, off, 64);
    obj += __shfl_down(obj, off, 64);
  }
  if (tid == 0) {
    box *= (1.f / 16.f); cls *= (1.f / 16.f); obj *= (1.f / 16.f);
    out[0] = 0.05f * box + 0.5f * cls + 1.0f * obj;
    out[1] = box;
    out[2] = cls;
    out[3] = obj;
  }
}

// ---------------------------------------------------------------------------
extern "C" void kernel_launch(void* const* d_in, const int* in_sizes, int n_in,
                              void* d_out, int out_size, void* d_ws, size_t ws_size,
                              hipStream_t stream)
{
  const float* pred = (const float*)d_in[0];   // (16,3,160,160,9) fp32
  const float* tgt  = (const float*)d_in[1];   // (16,32,5) fp32
  float* out = (float*)d_out;                  // 4 fp32

  char* ws = (char*)d_ws;
  Accum* acc = (Accum*)ws;                                        // 384 B
  int* blockCounts  = (int*)(ws + sizeof(Accum));                 // 16*300*4
  int* blockOffsets = blockCounts + kB * kNB;                     // 16*300*4
  unsigned long long* posBits =
      (unsigned long long*)(blockOffsets + kB * kNB);             // 16*1200*8
  // total ws use: 384 + 19200 + 19200 + 153600 = ~192 KB

  hipMemsetAsync(acc, 0, sizeof(Accum), stream);  // ws is poisoned each call

  pass1_kernel<<<dim3(kNB, kB), kBlk, 0, stream>>>(pred, tgt, acc, blockCounts, posBits);
  pass2_kernel<<<dim3(kB), 512, 0, stream>>>(blockCounts, blockOffsets);
  pass3_kernel<<<dim3(kNB, kB), kBlk, 0, stream>>>(pred, tgt, acc, blockOffsets, posBits);
  pass4_kernel<<<1, 64, 0, stream>>>(acc, out);
}

// Round 3
// 241.416 us; speedup vs baseline: 1.0319x; 1.0319x over previous
//
#include <hip/hip_runtime.h>
#include <cstdint>
#include <cstddef>

// Problem geometry (fixed by the reference setup_inputs()):
//   predictions: (16, 3, 160, 160, 9) fp32  -> per image N=76800 anchors x D=9
//   targets:     (16, 32, 5) fp32  [cls, x, y, w, h]
//   output: 4 fp32 scalars: total, box_loss, cls_loss, obj_loss
constexpr int kB     = 16;
constexpr int kN     = 76800;       // 3*160*160
constexpr int kD     = 9;
constexpr int kT     = 32;
constexpr int kBlk1  = 512;         // anchors per pass1/pass3 block
constexpr int kNB    = kN / kBlk1;  // 150 blocks per image (exact)
constexpr int kWords = kN / 64;     // 1200 ballot words per image

struct Accum {
  int   npos[kB];
  int   nneg[kB];
  float objPos[kB];
  float objNeg[kB];
  float sqSum[kB];
  float ceSum[kB];
};

// jax.nn.softplus(x) == logaddexp(x,0) == max(x,0) + log1p(exp(-|x|))
__device__ __forceinline__ float softplusf(float x) {
  return fmaxf(x, 0.f) + log1pf(expf(-fabsf(x)));
}

// ---------------------------------------------------------------------------
// Pass 0: derive per-target box corners/areas once, laid out SoA
// twork[b][comp][j], comp in {t1x,t1y,t2x,t2y,ta} -> wave-uniform s_load in pass1.
// ---------------------------------------------------------------------------
__global__ __launch_bounds__(kB * kT) void pass0_kernel(
    const float* __restrict__ tgt, float* __restrict__ twork)
{
  const int t = threadIdx.x;           // 0..511
  const int b = t >> 5, j = t & 31;
  const float* tp = tgt + ((size_t)b * kT + j) * 5;
  const float tx = tp[1], ty = tp[2], tw = tp[3], th = tp[4];
  const float t1x = tx - tw * 0.5f, t1y = ty - th * 0.5f;
  const float t2x = tx + tw * 0.5f, t2y = ty + th * 0.5f;
  float* w = twork + (size_t)b * 5 * kT;
  w[0 * kT + j] = t1x;
  w[1 * kT + j] = t1y;
  w[2 * kT + j] = t2x;
  w[3 * kT + j] = t2y;
  w[4 * kT + j] = (t2x - t1x) * (t2y - t1y);   // reference: prod(t2-t1)
}

// ---------------------------------------------------------------------------
// Pass 1: 2 anchors/thread; IoU-max over 32 targets (targets via SGPRs),
// pos/neg ballots -> posBits, per-block pos counts, per-image obj partials.
// ---------------------------------------------------------------------------
__global__ __launch_bounds__(256) void pass1_kernel(
    const float* __restrict__ pred, const float* __restrict__ twork,
    Accum* __restrict__ acc, int* __restrict__ blockCounts,
    unsigned long long* __restrict__ posBits)
{
  __shared__ float s_red[4][2];
  __shared__ int   s_cnt[4];

  const int b   = blockIdx.y;
  const int blk = blockIdx.x;
  const int tid = threadIdx.x;
  const float* tw = twork + (size_t)b * 5 * kT;   // uniform base

  const int i0 = blk * kBlk1 + tid;      // first anchor
  const int i1 = i0 + 256;               // second anchor
  const float* p0 = pred + ((size_t)b * kN + i0) * kD;
  const float* p1 = pred + ((size_t)b * kN + i1) * kD;

  const float ax = p0[0], ay = p0[1], aw = p0[2], ah = p0[3], aobj = p0[4];
  const float bx = p1[0], by = p1[1], bw = p1[2], bh = p1[3], bobj = p1[4];
  const float a1x = ax - aw * 0.5f, a1y = ay - ah * 0.5f;
  const float a2x = ax + aw * 0.5f, a2y = ay + ah * 0.5f;
  const float b1x = bx - bw * 0.5f, b1y = by - bh * 0.5f;
  const float b2x = bx + bw * 0.5f, b2y = by + bh * 0.5f;
  const float aa = (a2x - a1x) * (a2y - a1y);
  const float ba = (b2x - b1x) * (b2y - b1y);

  float bestA = -INFINITY, bestB = -INFINITY;
  #pragma unroll
  for (int j = 0; j < kT; ++j) {
    // wave-uniform target operands -> SGPRs (s_load), <=1 SGPR per VALU op
    const float t1x = tw[0 * kT + j];
    const float t1y = tw[1 * kT + j];
    const float t2x = tw[2 * kT + j];
    const float t2y = tw[3 * kT + j];
    const float ta  = tw[4 * kT + j];

    {
      const float lox = fmaxf(a1x, t1x), loy = fmaxf(a1y, t1y);
      const float hix = fminf(a2x, t2x), hiy = fminf(a2y, t2y);
      const float inter = fmaxf(hix - lox, 0.f) * fmaxf(hiy - loy, 0.f);
      const float iou = inter / (aa + ta - inter + 1e-6f);  // exact IEEE div
      bestA = fmaxf(bestA, iou);
    }
    {
      const float lox = fmaxf(b1x, t1x), loy = fmaxf(b1y, t1y);
      const float hix = fminf(b2x, t2x), hiy = fminf(b2y, t2y);
      const float inter = fmaxf(hix - lox, 0.f) * fmaxf(hiy - loy, 0.f);
      const float iou = inter / (ba + ta - inter + 1e-6f);
      bestB = fmaxf(bestB, iou);
    }
  }
  const bool posA = bestA > 0.5f, negA = bestA < 0.3f;
  const bool posB = bestB > 0.5f, negB = bestB < 0.3f;

  float op = (posA ? softplusf(-aobj) : 0.f) + (posB ? softplusf(-bobj) : 0.f);
  float on = (negA ? softplusf( aobj) : 0.f) + (negB ? softplusf( bobj) : 0.f);

  const int lane = tid & 63;
  const int wv   = tid >> 6;
  const unsigned long long pmA = __ballot(posA);
  const unsigned long long pmB = __ballot(posB);
  const unsigned long long nmA = __ballot(negA);
  const unsigned long long nmB = __ballot(negB);
  if (lane == 0) {
    // word for anchors [blk*512 + wv*64)  and  [blk*512 + 256 + wv*64)
    posBits[(size_t)b * kWords + blk * 8 + wv]     = pmA;
    posBits[(size_t)b * kWords + blk * 8 + 4 + wv] = pmB;
  }

  #pragma unroll
  for (int off = 32; off > 0; off >>= 1) {
    op += __shfl_down(op, off, 64);
    on += __shfl_down(on, off, 64);
  }
  int pc = __popcll(pmA) + __popcll(pmB);
  int nc = __popcll(nmA) + __popcll(nmB);
  if (lane == 0) {
    s_red[wv][0] = op; s_red[wv][1] = on;
    s_cnt[wv] = pc;
  }
  __syncthreads();
  if (tid == 0) {
    float sop = 0.f, son = 0.f; int pct = 0;
    #pragma unroll
    for (int w = 0; w < 4; ++w) { sop += s_red[w][0]; son += s_red[w][1]; pct += s_cnt[w]; }
    blockCounts[b * kNB + blk] = pct;
    atomicAdd(&acc->npos[b], pct);
    atomicAdd(&acc->objPos[b], sop);
    atomicAdd(&acc->objNeg[b], son);   // <- R2 bug: this line was missing
  }
  // nneg via one atomic per wave
  if (lane == 0) atomicAdd(&acc->nneg[b], nc);
}

// ---------------------------------------------------------------------------
// Pass 2: per image, exclusive scan of the 150 per-block pos counts.
// ---------------------------------------------------------------------------
__global__ __launch_bounds__(512) void pass2_kernel(
    const int* __restrict__ blockCounts, int* __restrict__ blockOffsets)
{
  __shared__ int s[512];
  const int b = blockIdx.x, t = threadIdx.x;
  const int v = (t < kNB) ? blockCounts[b * kNB + t] : 0;
  s[t] = v;
  __syncthreads();
  for (int off = 1; off < 512; off <<= 1) {
    const int add = (t >= off) ? s[t - off] : 0;
    __syncthreads();
    s[t] += add;
    __syncthreads();
  }
  if (t < kNB) blockOffsets[b * kNB + t] = s[t] - v;  // exclusive
}

// ---------------------------------------------------------------------------
// Pass 3: positives only — ordinal via ballot prefix + block offset,
// tidx = ordinal % 32, accumulate box SSE and class CE.  512 thr / block.
// ---------------------------------------------------------------------------
__global__ __launch_bounds__(kBlk1) void pass3_kernel(
    const float* __restrict__ pred, const float* __restrict__ tgt,
    Accum* __restrict__ acc, const int* __restrict__ blockOffsets,
    const unsigned long long* __restrict__ posBits)
{
  __shared__ float s_tx[kT], s_ty[kT];
  __shared__ int   s_tc[kT];
  __shared__ int   s_wtot[8];
  __shared__ float s_red[8][2];

  const int b = blockIdx.y, blk = blockIdx.x, tid = threadIdx.x;
  if (tid < kT) {
    const float* tp = tgt + ((size_t)b * kT + tid) * 5;
    s_tx[tid] = tp[1]; s_ty[tid] = tp[2];
    s_tc[tid] = (int)tp[0];
  }
  const int lane = tid & 63, wv = tid >> 6;          // wv in 0..7
  const unsigned long long mask = posBits[(size_t)b * kWords + blk * 8 + wv];
  if (lane == 0) s_wtot[wv] = __popcll(mask);
  __syncthreads();

  int base = blockOffsets[b * kNB + blk];
  for (int w = 0; w < wv; ++w) base += s_wtot[w];

  const bool pos = (mask >> lane) & 1ull;
  float sqc = 0.f, cec = 0.f;
  if (pos) {
    const int ord = base + __popcll(mask & ((1ull << lane) - 1ull));
    const int tix = ord & (kT - 1);                  // % 32, ord >= 0
    const int i = blk * kBlk1 + tid;
    const float* p = pred + ((size_t)b * kN + i) * kD;
    const float dx = p[0] - s_tx[tix];
    const float dy = p[1] - s_ty[tix];
    sqc = dx * dx + dy * dy;
    const float c0 = p[5], c1 = p[6], c2 = p[7], c3 = p[8];
    const float m = fmaxf(fmaxf(c0, c1), fmaxf(c2, c3));
    const float lse = m + logf(expf(c0 - m) + expf(c1 - m) + expf(c2 - m) + expf(c3 - m));
    const int tc = s_tc[tix];
    const float cv = (tc == 0) ? c0 : (tc == 1) ? c1 : (tc == 2) ? c2 : c3;
    cec = lse - cv;
  }
  #pragma unroll
  for (int off = 32; off > 0; off >>= 1) {
    sqc += __shfl_down(sqc, off, 64);
    cec += __shfl_down(cec, off, 64);
  }
  if (lane == 0) { s_red[wv][0] = sqc; s_red[wv][1] = cec; }
  __syncthreads();
  if (tid == 0) {
    float ss = 0.f, cs = 0.f;
    #pragma unroll
    for (int w = 0; w < 8; ++w) { ss += s_red[w][0]; cs += s_red[w][1]; }
    atomicAdd(&acc->sqSum[b], ss);
    atomicAdd(&acc->ceSum[b], cs);
  }
}

// ---------------------------------------------------------------------------
// Pass 4: finalize 4 scalars.
// ---------------------------------------------------------------------------
__global__ __launch_bounds__(64) void pass4_kernel(
    const Accum* __restrict__ acc, float* __restrict__ out)
{
  const int tid = threadIdx.x;
  float box = 0.f, cls = 0.f, obj = 0.f;
  if (tid < kB) {
    const float np_ = (float)acc->npos[tid];
    const float nn  = (float)acc->nneg[tid];
    if (np_ > 0.f) {
      box = acc->sqSum[tid] / (2.0f * np_);
      cls = acc->ceSum[tid] / np_;
      obj = acc->objPos[tid] / np_;
    }
    if (nn > 0.f) obj += acc->objNeg[tid] / nn;
  }
  #pragma unroll
  for (int off = 32; off > 0; off >>= 1) {
    box += __shfl_down(box, off, 64);
    cls += __shfl_down(cls, off, 64);
    obj += __shfl_down(obj, off, 64);
  }
  if (tid == 0) {
    box *= (1.f / 16.f); cls *= (1.f / 16.f); obj *= (1.f / 16.f);
    out[0] = 0.05f * box + 0.5f * cls + 1.0f * obj;
    out[1] = box;
    out[2] = cls;
    out[3] = obj;
  }
}

// ---------------------------------------------------------------------------
extern "C" void kernel_launch(void* const* d_in, const int* in_sizes, int n_in,
                              void* d_out, int out_size, void* d_ws, size_t ws_size,
                              hipStream_t stream)
{
  const float* pred = (const float*)d_in[0];   // (16,3,160,160,9) fp32
  const float* tgt  = (const float*)d_in[1];   // (16,32,5) fp32
  float* out = (float*)d_out;                  // 4 fp32

  char* ws = (char*)d_ws;
  Accum* acc = (Accum*)ws;                                        // 384 B
  float* twork = (float*)(ws + 512);                              // 16*5*32*4 = 10 KB
  int* blockCounts  = (int*)(ws + 512 + 10240);                   // 16*150*4
  int* blockOffsets = blockCounts + kB * kNB;                     // 16*150*4
  unsigned long long* posBits =
      (unsigned long long*)(blockOffsets + kB * kNB);             // 16*1200*8
  // total ws use < 200 KB

  hipMemsetAsync(acc, 0, sizeof(Accum), stream);  // ws is poisoned each call

  pass0_kernel<<<1, kB * kT, 0, stream>>>(tgt, twork);
  pass1_kernel<<<dim3(kNB, kB), 256, 0, stream>>>(pred, twork, acc, blockCounts, posBits);
  pass2_kernel<<<dim3(kB), 512, 0, stream>>>(blockCounts, blockOffsets);
  pass3_kernel<<<dim3(kNB, kB), kBlk1, 0, stream>>>(pred, tgt, acc, blockOffsets, posBits);
  pass4_kernel<<<1, 64, 0, stream>>>(acc, out);
}

// Round 4
// 220.751 us; speedup vs baseline: 1.1285x; 1.0936x over previous
//
#include <hip/hip_runtime.h>
#include <cstdint>
#include <cstddef>

// predictions: (16, 3, 160, 160, 9) fp32 -> per image N=76800 anchors x D=9
// targets:     (16, 32, 5) fp32 [cls, x, y, w, h]
// output: 4 fp32 scalars: total, box_loss, cls_loss, obj_loss
constexpr int kB     = 16;
constexpr int kN     = 76800;
constexpr int kD     = 9;
constexpr int kT     = 32;
constexpr int kBlk1  = 256;          // pass1 block (anchors/thread = 1)
constexpr int kNB1   = kN / kBlk1;   // 300 pass1 blocks per image
constexpr int kBlk3  = 512;          // pass3 block
constexpr int kNB3   = kN / kBlk3;   // 150 pass3 blocks per image
constexpr int kWords = kN / 64;      // 1200 ballot words per image

struct Accum {
  int   npos[kB];
  int   nneg[kB];
  float objPos[kB];
  float objNeg[kB];
  float sqSum[kB];
  float ceSum[kB];
};

// jax.nn.softplus(x) == max(x,0) + log1p(exp(-|x|))
__device__ __forceinline__ float softplusf(float x) {
  return fmaxf(x, 0.f) + log1pf(expf(-fabsf(x)));
}

// ---------------------------------------------------------------------------
// Pass 0: derived target boxes, SoA: twork[b][comp][j], comp={t1x,t1y,t2x,t2y,ta}
// ---------------------------------------------------------------------------
__global__ __launch_bounds__(kB * kT) void pass0_kernel(
    const float* __restrict__ tgt, float* __restrict__ twork)
{
  const int t = threadIdx.x;           // 0..511
  const int b = t >> 5, j = t & 31;
  const float* tp = tgt + ((size_t)b * kT + j) * 5;
  const float tx = tp[1], ty = tp[2], tw = tp[3], th = tp[4];
  const float t1x = tx - tw * 0.5f, t1y = ty - th * 0.5f;
  const float t2x = tx + tw * 0.5f, t2y = ty + th * 0.5f;
  float* w = twork + (size_t)b * 5 * kT;
  w[0 * kT + j] = t1x;
  w[1 * kT + j] = t1y;
  w[2 * kT + j] = t2x;
  w[3 * kT + j] = t2y;
  w[4 * kT + j] = (t2x - t1x) * (t2y - t1y);   // reference: prod(t2-t1)
}

// ---------------------------------------------------------------------------
// Pass 1: 1 anchor/thread. Division-free threshold tests:
//   iou>0.5  <=>  d>=0 && inter>0.5*d        (d = ((pa+ta)-inter)+1e-6)
//   iou<0.3  <=>  d<0  || inter<0.3f*d
// pos/neg ballots -> posBits; per-block counts; per-image obj partials.
// ---------------------------------------------------------------------------
__global__ __launch_bounds__(kBlk1) void pass1_kernel(
    const float* __restrict__ pred, const float* __restrict__ twork,
    Accum* __restrict__ acc, int* __restrict__ blockCounts,
    unsigned long long* __restrict__ posBits)
{
  __shared__ float s_red[4][2];
  __shared__ int   s_cnt[4][2];

  const int b   = blockIdx.y;
  const int blk = blockIdx.x;
  const int tid = threadIdx.x;
  const float* tw = twork + (size_t)b * 5 * kT;   // wave-uniform base

  const int i = blk * kBlk1 + tid;
  const float* p = pred + ((size_t)b * kN + i) * kD;
  const float px = p[0], py = p[1], pw = p[2], ph = p[3], pobj = p[4];
  const float p1x = px - pw * 0.5f, p1y = py - ph * 0.5f;
  const float p2x = px + pw * 0.5f, p2y = py + ph * 0.5f;
  const float pa  = (p2x - p1x) * (p2y - p1y);

  bool posAny = false, negAll = true;
  #pragma unroll
  for (int j = 0; j < kT; ++j) {
    const float t1x = tw[0 * kT + j];
    const float t1y = tw[1 * kT + j];
    const float t2x = tw[2 * kT + j];
    const float t2y = tw[3 * kT + j];
    const float ta  = tw[4 * kT + j];
    const float lox = fmaxf(p1x, t1x), loy = fmaxf(p1y, t1y);
    const float hix = fminf(p2x, t2x), hiy = fminf(p2y, t2y);
    const float inter = fmaxf(hix - lox, 0.f) * fmaxf(hiy - loy, 0.f);
    const float d = ((pa + ta) - inter) + 1e-6f;   // reference eval order
    posAny = posAny || ((d >= 0.f) && (inter > 0.5f * d));
    negAll = negAll && ((d <  0.f) || (inter < 0.3f * d));
  }
  const bool pos = posAny;
  const bool neg = negAll;

  const float op = pos ? softplusf(-pobj) : 0.f;
  const float on = neg ? softplusf( pobj) : 0.f;

  const int lane = tid & 63;
  const int wv   = tid >> 6;
  const unsigned long long pmask = __ballot(pos);
  const unsigned long long nmask = __ballot(neg);
  if (lane == 0)
    posBits[(size_t)b * kWords + blk * 4 + wv] = pmask;

  float rop = op, ron = on;
  #pragma unroll
  for (int off = 32; off > 0; off >>= 1) {
    rop += __shfl_down(rop, off, 64);
    ron += __shfl_down(ron, off, 64);
  }
  if (lane == 0) {
    s_red[wv][0] = rop;              s_red[wv][1] = ron;
    s_cnt[wv][0] = __popcll(pmask);  s_cnt[wv][1] = __popcll(nmask);
  }
  __syncthreads();
  if (tid == 0) {
    float sop = 0.f, son = 0.f; int pc = 0, nc = 0;
    #pragma unroll
    for (int w = 0; w < 4; ++w) {
      sop += s_red[w][0]; son += s_red[w][1];
      pc  += s_cnt[w][0]; nc  += s_cnt[w][1];
    }
    blockCounts[b * kNB1 + blk] = pc;   // non-atomic, one writer per slot
    atomicAdd(&acc->npos[b], pc);
    atomicAdd(&acc->nneg[b], nc);
    atomicAdd(&acc->objPos[b], sop);
    atomicAdd(&acc->objNeg[b], son);
  }
}

// ---------------------------------------------------------------------------
// Pass 2: per image, exclusive scan of the 300 per-block pos counts.
// ---------------------------------------------------------------------------
__global__ __launch_bounds__(512) void pass2_kernel(
    const int* __restrict__ blockCounts, int* __restrict__ blockOffsets)
{
  __shared__ int s[512];
  const int b = blockIdx.x, t = threadIdx.x;
  const int v = (t < kNB1) ? blockCounts[b * kNB1 + t] : 0;
  s[t] = v;
  __syncthreads();
  for (int off = 1; off < 512; off <<= 1) {
    const int add = (t >= off) ? s[t - off] : 0;
    __syncthreads();
    s[t] += add;
    __syncthreads();
  }
  if (t < kNB1) blockOffsets[b * kNB1 + t] = s[t] - v;  // exclusive
}

// ---------------------------------------------------------------------------
// Pass 3: positives only (512 thr, 150 blocks/image). Ordinal via
// block offset (at pass1-block granularity) + in-window ballot prefix.
// ---------------------------------------------------------------------------
__global__ __launch_bounds__(kBlk3) void pass3_kernel(
    const float* __restrict__ pred, const float* __restrict__ tgt,
    Accum* __restrict__ acc, const int* __restrict__ blockOffsets,
    const unsigned long long* __restrict__ posBits)
{
  __shared__ float s_tx[kT], s_ty[kT];
  __shared__ int   s_tc[kT];
  __shared__ int   s_wtot[8];
  __shared__ float s_red[8][2];

  const int b = blockIdx.y, blk = blockIdx.x, tid = threadIdx.x;
  const int lane = tid & 63, wv = tid >> 6;          // wv in 0..7
  const unsigned long long mask = posBits[(size_t)b * kWords + blk * 8 + wv];
  if (lane == 0) s_wtot[wv] = __popcll(mask);
  __syncthreads();

  int tot = 0;
  #pragma unroll
  for (int w = 0; w < 8; ++w) tot += s_wtot[w];
  if (tot == 0) return;                               // no positives here

  if (tid < kT) {
    const float* tp = tgt + ((size_t)b * kT + tid) * 5;
    s_tx[tid] = tp[1]; s_ty[tid] = tp[2];
    s_tc[tid] = (int)tp[0];
  }
  __syncthreads();

  // positives before this pass3-block = exclusive scan at pass1 granularity
  int base = blockOffsets[b * kNB1 + blk * 2];
  for (int w = 0; w < wv; ++w) base += s_wtot[w];

  const bool pos = (mask >> lane) & 1ull;
  float sqc = 0.f, cec = 0.f;
  if (pos) {
    const int ord = base + __popcll(mask & ((1ull << lane) - 1ull));
    const int tix = ord & (kT - 1);                  // % 32, ord >= 0
    const int i = blk * kBlk3 + tid;
    const float* p = pred + ((size_t)b * kN + i) * kD;
    const float dx = p[0] - s_tx[tix];
    const float dy = p[1] - s_ty[tix];
    sqc = dx * dx + dy * dy;
    const float c0 = p[5], c1 = p[6], c2 = p[7], c3 = p[8];
    const float m = fmaxf(fmaxf(c0, c1), fmaxf(c2, c3));
    const float lse = m + logf(expf(c0 - m) + expf(c1 - m) + expf(c2 - m) + expf(c3 - m));
    const int tc = s_tc[tix];
    const float cv = (tc == 0) ? c0 : (tc == 1) ? c1 : (tc == 2) ? c2 : c3;
    cec = lse - cv;
  }
  #pragma unroll
  for (int off = 32; off > 0; off >>= 1) {
    sqc += __shfl_down(sqc, off, 64);
    cec += __shfl_down(cec, off, 64);
  }
  if (lane == 0) { s_red[wv][0] = sqc; s_red[wv][1] = cec; }
  __syncthreads();
  if (tid == 0) {
    float ss = 0.f, cs = 0.f;
    #pragma unroll
    for (int w = 0; w < 8; ++w) { ss += s_red[w][0]; cs += s_red[w][1]; }
    atomicAdd(&acc->sqSum[b], ss);
    atomicAdd(&acc->ceSum[b], cs);
  }
}

// ---------------------------------------------------------------------------
// Pass 4: finalize 4 scalars.
// ---------------------------------------------------------------------------
__global__ __launch_bounds__(64) void pass4_kernel(
    const Accum* __restrict__ acc, float* __restrict__ out)
{
  const int tid = threadIdx.x;
  float box = 0.f, cls = 0.f, obj = 0.f;
  if (tid < kB) {
    const float np_ = (float)acc->npos[tid];
    const float nn  = (float)acc->nneg[tid];
    if (np_ > 0.f) {
      box = acc->sqSum[tid] / (2.0f * np_);
      cls = acc->ceSum[tid] / np_;
      obj = acc->objPos[tid] / np_;
    }
    if (nn > 0.f) obj += acc->objNeg[tid] / nn;
  }
  #pragma unroll
  for (int off = 32; off > 0; off >>= 1) {
    box += __shfl_down(box, off, 64);
    cls += __shfl_down(cls, off, 64);
    obj += __shfl_down(obj, off, 64);
  }
  if (tid == 0) {
    box *= (1.f / 16.f); cls *= (1.f / 16.f); obj *= (1.f / 16.f);
    out[0] = 0.05f * box + 0.5f * cls + 1.0f * obj;
    out[1] = box;
    out[2] = cls;
    out[3] = obj;
  }
}

// ---------------------------------------------------------------------------
extern "C" void kernel_launch(void* const* d_in, const int* in_sizes, int n_in,
                              void* d_out, int out_size, void* d_ws, size_t ws_size,
                              hipStream_t stream)
{
  const float* pred = (const float*)d_in[0];
  const float* tgt  = (const float*)d_in[1];
  float* out = (float*)d_out;

  char* ws = (char*)d_ws;
  Accum* acc = (Accum*)ws;                                        // 384 B
  float* twork = (float*)(ws + 512);                              // 10 KB
  int* blockCounts  = (int*)(ws + 512 + 10240);                   // 16*300*4
  int* blockOffsets = blockCounts + kB * kNB1;                    // 16*300*4
  unsigned long long* posBits =
      (unsigned long long*)(blockOffsets + kB * kNB1);            // 16*1200*8
  // total ws use ~203 KB

  hipMemsetAsync(acc, 0, sizeof(Accum), stream);

  pass0_kernel<<<1, kB * kT, 0, stream>>>(tgt, twork);
  pass1_kernel<<<dim3(kNB1, kB), kBlk1, 0, stream>>>(pred, twork, acc, blockCounts, posBits);
  pass2_kernel<<<dim3(kB), 512, 0, stream>>>(blockCounts, blockOffsets);
  pass3_kernel<<<dim3(kNB3, kB), kBlk3, 0, stream>>>(pred, tgt, acc, blockOffsets, posBits);
  pass4_kernel<<<1, 64, 0, stream>>>(acc, out);
}

// Round 5
// 117.843 us; speedup vs baseline: 2.1139x; 1.8733x over previous
//
#include <hip/hip_runtime.h>
#include <cstdint>
#include <cstddef>

// predictions: (16, 3, 160, 160, 9) fp32 -> per image N=76800 anchors x D=9
// targets:     (16, 32, 5) fp32 [cls, x, y, w, h]
// output: 4 fp32 scalars: total, box_loss, cls_loss, obj_loss
constexpr int kB     = 16;
constexpr int kN     = 76800;
constexpr int kD     = 9;
constexpr int kT     = 32;
constexpr int kBlk1  = 256;          // pass1 block (1 anchor/thread)
constexpr int kNB1   = kN / kBlk1;   // 300 pass1 blocks per image
constexpr int kBlk3  = 512;          // pass3 block
constexpr int kNB3   = kN / kBlk3;   // 150 pass3 blocks per image
constexpr int kWords = kN / 64;      // 1200 ballot words per image

struct ImgStats { int npos; int nneg; float objPos; float objNeg; };  // 16 B

// jax.nn.softplus(x) == max(x,0) + log1p(exp(-|x|))
__device__ __forceinline__ float softplusf(float x) {
  return fmaxf(x, 0.f) + log1pf(expf(-fabsf(x)));
}

// ---------------------------------------------------------------------------
// Pass 0: derived target boxes, SoA: twork[b][comp][j], comp={t1x,t1y,t2x,t2y,ta}
// ---------------------------------------------------------------------------
__global__ __launch_bounds__(kB * kT) void pass0_kernel(
    const float* __restrict__ tgt, float* __restrict__ twork)
{
  const int t = threadIdx.x;           // 0..511
  const int b = t >> 5, j = t & 31;
  const float* tp = tgt + ((size_t)b * kT + j) * 5;
  const float tx = tp[1], ty = tp[2], tw = tp[3], th = tp[4];
  const float t1x = tx - tw * 0.5f, t1y = ty - th * 0.5f;
  const float t2x = tx + tw * 0.5f, t2y = ty + th * 0.5f;
  float* w = twork + (size_t)b * 5 * kT;
  w[0 * kT + j] = t1x;
  w[1 * kT + j] = t1y;
  w[2 * kT + j] = t2x;
  w[3 * kT + j] = t2y;
  w[4 * kT + j] = (t2x - t1x) * (t2y - t1y);   // reference: prod(t2-t1)
}

// ---------------------------------------------------------------------------
// Pass 1: 1 anchor/thread, division-free threshold tests.  NO ATOMICS:
// per-block partials to distinct slots (counts / nneg / objP / objN).
// ---------------------------------------------------------------------------
__global__ __launch_bounds__(kBlk1) void pass1_kernel(
    const float* __restrict__ pred, const float* __restrict__ twork,
    int* __restrict__ blockCounts, int* __restrict__ blockNneg,
    float* __restrict__ blockObjP, float* __restrict__ blockObjN,
    unsigned long long* __restrict__ posBits)
{
  __shared__ float s_red[4][2];
  __shared__ int   s_cnt[4][2];

  const int b   = blockIdx.y;
  const int blk = blockIdx.x;
  const int tid = threadIdx.x;
  const float* tw = twork + (size_t)b * 5 * kT;   // wave-uniform base

  const int i = blk * kBlk1 + tid;
  const float* p = pred + ((size_t)b * kN + i) * kD;
  const float px = p[0], py = p[1], pw = p[2], ph = p[3], pobj = p[4];
  const float p1x = px - pw * 0.5f, p1y = py - ph * 0.5f;
  const float p2x = px + pw * 0.5f, p2y = py + ph * 0.5f;
  const float pa  = (p2x - p1x) * (p2y - p1y);

  bool posAny = false, negAll = true;
  #pragma unroll
  for (int j = 0; j < kT; ++j) {
    const float t1x = tw[0 * kT + j];
    const float t1y = tw[1 * kT + j];
    const float t2x = tw[2 * kT + j];
    const float t2y = tw[3 * kT + j];
    const float ta  = tw[4 * kT + j];
    const float lox = fmaxf(p1x, t1x), loy = fmaxf(p1y, t1y);
    const float hix = fminf(p2x, t2x), hiy = fminf(p2y, t2y);
    const float inter = fmaxf(hix - lox, 0.f) * fmaxf(hiy - loy, 0.f);
    const float d = ((pa + ta) - inter) + 1e-6f;   // reference eval order
    posAny = posAny || ((d >= 0.f) && (inter > 0.5f * d));
    negAll = negAll && ((d <  0.f) || (inter < 0.3f * d));
  }
  const bool pos = posAny;
  const bool neg = negAll;

  const float op = pos ? softplusf(-pobj) : 0.f;
  const float on = neg ? softplusf( pobj) : 0.f;

  const int lane = tid & 63;
  const int wv   = tid >> 6;
  const unsigned long long pmask = __ballot(pos);
  const unsigned long long nmask = __ballot(neg);
  if (lane == 0)
    posBits[(size_t)b * kWords + blk * 4 + wv] = pmask;

  float rop = op, ron = on;
  #pragma unroll
  for (int off = 32; off > 0; off >>= 1) {
    rop += __shfl_down(rop, off, 64);
    ron += __shfl_down(ron, off, 64);
  }
  if (lane == 0) {
    s_red[wv][0] = rop;              s_red[wv][1] = ron;
    s_cnt[wv][0] = __popcll(pmask);  s_cnt[wv][1] = __popcll(nmask);
  }
  __syncthreads();
  if (tid == 0) {
    float sop = 0.f, son = 0.f; int pc = 0, nc = 0;
    #pragma unroll
    for (int w = 0; w < 4; ++w) {
      sop += s_red[w][0]; son += s_red[w][1];
      pc  += s_cnt[w][0]; nc  += s_cnt[w][1];
    }
    const int slot = b * kNB1 + blk;   // one writer per slot, no atomics
    blockCounts[slot] = pc;
    blockNneg[slot]   = nc;
    blockObjP[slot]   = sop;
    blockObjN[slot]   = son;
  }
}

// ---------------------------------------------------------------------------
// Pass 2: per image — exclusive scan of 300 pos counts (for pass3 ordinals)
// + reduce nneg/objP/objN + total npos into ImgStats.  16 blocks x 512.
// ---------------------------------------------------------------------------
__global__ __launch_bounds__(512) void pass2_kernel(
    const int* __restrict__ blockCounts, const int* __restrict__ blockNneg,
    const float* __restrict__ blockObjP, const float* __restrict__ blockObjN,
    int* __restrict__ blockOffsets, ImgStats* __restrict__ stats)
{
  __shared__ int s[512];
  __shared__ float s_op[8], s_on[8];
  __shared__ int   s_nn[8];

  const int b = blockIdx.x, t = threadIdx.x;
  const bool live = (t < kNB1);
  const int v = live ? blockCounts[b * kNB1 + t] : 0;
  int   nn = live ? blockNneg[b * kNB1 + t] : 0;
  float op = live ? blockObjP[b * kNB1 + t] : 0.f;
  float on = live ? blockObjN[b * kNB1 + t] : 0.f;

  s[t] = v;
  __syncthreads();
  for (int off = 1; off < 512; off <<= 1) {
    const int add = (t >= off) ? s[t - off] : 0;
    __syncthreads();
    s[t] += add;
    __syncthreads();
  }
  if (live) blockOffsets[b * kNB1 + t] = s[t] - v;  // exclusive

  const int lane = t & 63, wv = t >> 6;
  #pragma unroll
  for (int off = 32; off > 0; off >>= 1) {
    nn += __shfl_down(nn, off, 64);
    op += __shfl_down(op, off, 64);
    on += __shfl_down(on, off, 64);
  }
  if (lane == 0) { s_nn[wv] = nn; s_op[wv] = op; s_on[wv] = on; }
  __syncthreads();
  if (t == 0) {
    int tn = 0; float top = 0.f, ton = 0.f;
    #pragma unroll
    for (int w = 0; w < 8; ++w) { tn += s_nn[w]; top += s_op[w]; ton += s_on[w]; }
    ImgStats st;
    st.npos = s[511];          // inclusive-scan total
    st.nneg = tn;
    st.objPos = top;
    st.objNeg = ton;
    stats[b] = st;
  }
}

// ---------------------------------------------------------------------------
// Pass 3: positives only.  NO ATOMICS: per-block (sq, ce) partials.
// ---------------------------------------------------------------------------
__global__ __launch_bounds__(kBlk3) void pass3_kernel(
    const float* __restrict__ pred, const float* __restrict__ tgt,
    const int* __restrict__ blockOffsets,
    const unsigned long long* __restrict__ posBits,
    float* __restrict__ p3sq, float* __restrict__ p3ce)
{
  __shared__ float s_tx[kT], s_ty[kT];
  __shared__ int   s_tc[kT];
  __shared__ int   s_wtot[8];
  __shared__ float s_red[8][2];

  const int b = blockIdx.y, blk = blockIdx.x, tid = threadIdx.x;
  const int slot = b * kNB3 + blk;
  const int lane = tid & 63, wv = tid >> 6;          // wv in 0..7
  const unsigned long long mask = posBits[(size_t)b * kWords + blk * 8 + wv];
  if (lane == 0) s_wtot[wv] = __popcll(mask);
  __syncthreads();

  int tot = 0;
  #pragma unroll
  for (int w = 0; w < 8; ++w) tot += s_wtot[w];
  if (tot == 0) {                                    // must still define slot
    if (tid == 0) { p3sq[slot] = 0.f; p3ce[slot] = 0.f; }
    return;
  }

  if (tid < kT) {
    const float* tp = tgt + ((size_t)b * kT + tid) * 5;
    s_tx[tid] = tp[1]; s_ty[tid] = tp[2];
    s_tc[tid] = (int)tp[0];
  }
  __syncthreads();

  int base = blockOffsets[b * kNB1 + blk * 2];
  for (int w = 0; w < wv; ++w) base += s_wtot[w];

  const bool pos = (mask >> lane) & 1ull;
  float sqc = 0.f, cec = 0.f;
  if (pos) {
    const int ord = base + __popcll(mask & ((1ull << lane) - 1ull));
    const int tix = ord & (kT - 1);                  // % 32, ord >= 0
    const int i = blk * kBlk3 + tid;
    const float* p = pred + ((size_t)b * kN + i) * kD;
    const float dx = p[0] - s_tx[tix];
    const float dy = p[1] - s_ty[tix];
    sqc = dx * dx + dy * dy;
    const float c0 = p[5], c1 = p[6], c2 = p[7], c3 = p[8];
    const float m = fmaxf(fmaxf(c0, c1), fmaxf(c2, c3));
    const float lse = m + logf(expf(c0 - m) + expf(c1 - m) + expf(c2 - m) + expf(c3 - m));
    const int tc = s_tc[tix];
    const float cv = (tc == 0) ? c0 : (tc == 1) ? c1 : (tc == 2) ? c2 : c3;
    cec = lse - cv;
  }
  #pragma unroll
  for (int off = 32; off > 0; off >>= 1) {
    sqc += __shfl_down(sqc, off, 64);
    cec += __shfl_down(cec, off, 64);
  }
  if (lane == 0) { s_red[wv][0] = sqc; s_red[wv][1] = cec; }
  __syncthreads();
  if (tid == 0) {
    float ss = 0.f, cs = 0.f;
    #pragma unroll
    for (int w = 0; w < 8; ++w) { ss += s_red[w][0]; cs += s_red[w][1]; }
    p3sq[slot] = ss;                                 // plain store
    p3ce[slot] = cs;
  }
}

// ---------------------------------------------------------------------------
// Pass 4: reduce pass3 partials per image, finalize 4 scalars.  1 block x 256.
// ---------------------------------------------------------------------------
__global__ __launch_bounds__(256) void pass4_kernel(
    const ImgStats* __restrict__ stats,
    const float* __restrict__ p3sq, const float* __restrict__ p3ce,
    float* __restrict__ out)
{
  __shared__ float s_sq[16][17], s_ce[16][17];
  const int tid = threadIdx.x;
  const int b = tid & 15, g = tid >> 4;              // image, group
  float sq = 0.f, ce = 0.f;
  for (int k = g; k < kNB3; k += 16) {
    sq += p3sq[b * kNB3 + k];
    ce += p3ce[b * kNB3 + k];
  }
  s_sq[g][b] = sq; s_ce[g][b] = ce;
  __syncthreads();

  float box = 0.f, cls = 0.f, obj = 0.f;
  if (tid < kB) {
    float ssq = 0.f, sce = 0.f;
    #pragma unroll
    for (int gg = 0; gg < 16; ++gg) { ssq += s_sq[gg][tid]; sce += s_ce[gg][tid]; }
    const ImgStats st = stats[tid];
    const float np_ = (float)st.npos;
    const float nn  = (float)st.nneg;
    if (np_ > 0.f) {
      box = ssq / (2.0f * np_);
      cls = sce / np_;
      obj = st.objPos / np_;
    }
    if (nn > 0.f) obj += st.objNeg / nn;
  }
  #pragma unroll
  for (int off = 8; off > 0; off >>= 1) {
    box += __shfl_down(box, off, 64);
    cls += __shfl_down(cls, off, 64);
    obj += __shfl_down(obj, off, 64);
  }
  if (tid == 0) {
    box *= (1.f / 16.f); cls *= (1.f / 16.f); obj *= (1.f / 16.f);
    out[0] = 0.05f * box + 0.5f * cls + 1.0f * obj;
    out[1] = box;
    out[2] = cls;
    out[3] = obj;
  }
}

// ---------------------------------------------------------------------------
extern "C" void kernel_launch(void* const* d_in, const int* in_sizes, int n_in,
                              void* d_out, int out_size, void* d_ws, size_t ws_size,
                              hipStream_t stream)
{
  const float* pred = (const float*)d_in[0];
  const float* tgt  = (const float*)d_in[1];
  float* out = (float*)d_out;

  char* ws = (char*)d_ws;
  float* twork        = (float*)(ws);                  // 10240 B
  int*   blockCounts  = (int*)(ws + 10240);            // 19200 B
  int*   blockNneg    = (int*)(ws + 29440);            // 19200 B
  float* blockObjP    = (float*)(ws + 48640);          // 19200 B
  float* blockObjN    = (float*)(ws + 67840);          // 19200 B
  int*   blockOffsets = (int*)(ws + 87040);            // 19200 B
  ImgStats* stats     = (ImgStats*)(ws + 106240);      // 256 B
  unsigned long long* posBits =
      (unsigned long long*)(ws + 106496);              // 153600 B (8-aligned)
  float* p3sq         = (float*)(ws + 260096);         // 9600 B
  float* p3ce         = (float*)(ws + 269696);         // 9600 B -> 279296 total

  // every ws word read is written by an earlier pass this call: no memset.
  pass0_kernel<<<1, kB * kT, 0, stream>>>(tgt, twork);
  pass1_kernel<<<dim3(kNB1, kB), kBlk1, 0, stream>>>(
      pred, twork, blockCounts, blockNneg, blockObjP, blockObjN, posBits);
  pass2_kernel<<<dim3(kB), 512, 0, stream>>>(
      blockCounts, blockNneg, blockObjP, blockObjN, blockOffsets, stats);
  pass3_kernel<<<dim3(kNB3, kB), kBlk3, 0, stream>>>(
      pred, tgt, blockOffsets, posBits, p3sq, p3ce);
  pass4_kernel<<<1, 256, 0, stream>>>(stats, p3sq, p3ce, out);
}